// Round 2
// baseline (4541.661 us; speedup 1.0000x reference)
//
#include <hip/hip_runtime.h>
#include <math.h>

#define N_NODES 100000
#define N_EDGES 1600000
#define F_IN 92
#define E_IN 50
#define D 64
#define N_LAYERS 3
#define N_GRAPHS 512
#define BN_EPS 1e-5f

__device__ __forceinline__ float silu_f(float x) {
    return x / (1.0f + __expf(-x));
}

// ---------------- CSR build ----------------
__global__ __launch_bounds__(256) void hist_kernel(
    const int* __restrict__ dst, int* __restrict__ deg) {
    for (int e = blockIdx.x * 256 + threadIdx.x; e < N_EDGES; e += gridDim.x * 256)
        atomicAdd(&deg[dst[e]], 1);
}

__global__ __launch_bounds__(1024) void scan_kernel(
    const int* __restrict__ deg, int* __restrict__ row_start,
    int* __restrict__ cursor) {
    __shared__ int part[1024];
    int t = threadIdx.x;
    const int CH = (N_NODES + 1023) / 1024;
    int lo = t * CH, hi = min(lo + CH, N_NODES);
    int s = 0;
    for (int i = lo; i < hi; ++i) s += deg[i];
    part[t] = s;
    __syncthreads();
    for (int off = 1; off < 1024; off <<= 1) {
        int v = (t >= off) ? part[t - off] : 0;
        __syncthreads();
        part[t] += v;
        __syncthreads();
    }
    int base = (t == 0) ? 0 : part[t - 1];
    for (int i = lo; i < hi; ++i) {
        int dg = deg[i];
        row_start[i] = base;
        cursor[i] = base;
        base += dg;
    }
    if (t == 1023) row_start[N_NODES] = base;
}

__global__ __launch_bounds__(256) void scatter_kernel(
    const int* __restrict__ dst, int* __restrict__ cursor,
    int* __restrict__ csr) {
    for (int e = blockIdx.x * 256 + threadIdx.x; e < N_EDGES; e += gridDim.x * 256) {
        int pos = atomicAdd(&cursor[dst[e]], 1);
        csr[pos] = e;
    }
}

// ---------------- dense stages ----------------
// h = silu(x @ pre_w + pre_b)
__global__ __launch_bounds__(256) void pre_fc_kernel(
    const float* __restrict__ x, const float* __restrict__ w,
    const float* __restrict__ b, float* __restrict__ h) {
    __shared__ float xs[4][F_IN];
    int d = threadIdx.x, yy = threadIdx.y;
    int node = blockIdx.x * 4 + yy;
    if (node < N_NODES) {
        const float* xrow = x + (long)node * F_IN;
        for (int i = d; i < F_IN; i += 64) xs[yy][i] = xrow[i];
    }
    __syncthreads();
    if (node >= N_NODES) return;
    float acc = b[d];
#pragma unroll 4
    for (int i = 0; i < F_IN; ++i) acc = fmaf(xs[yy][i], w[i * D + d], acc);
    h[(long)node * D + d] = silu_f(acc);
}

// k,q,v projections fused
__global__ __launch_bounds__(256) void node_proj_kernel(
    const float* __restrict__ h,
    const float* __restrict__ Wk, const float* __restrict__ bk,
    const float* __restrict__ Wq, const float* __restrict__ bq,
    const float* __restrict__ Wv, const float* __restrict__ bv,
    float* __restrict__ ko, float* __restrict__ qo, float* __restrict__ vo) {
    __shared__ float hs[4][D];
    int d = threadIdx.x, yy = threadIdx.y;
    int node = blockIdx.x * 4 + yy;
    if (node < N_NODES) hs[yy][d] = h[(long)node * D + d];
    __syncthreads();
    if (node >= N_NODES) return;
    float ak = bk[d], aq = bq[d], av = bv[d];
#pragma unroll 8
    for (int i = 0; i < D; ++i) {
        float hv = hs[yy][i];
        ak = fmaf(hv, Wk[i * D + d], ak);
        aq = fmaf(hv, Wq[i * D + d], aq);
        av = fmaf(hv, Wv[i * D + d], av);
    }
    long off = (long)node * D + d;
    ko[off] = ak; qo[off] = aq; vo[off] = av;
}

// One wave per node: aggregate messages over CSR edges + fused skip-GEMM.
// hnew = sum_e silu(k[n]+q[s]+2e)*(v[s]+e) + h@Wskip + bias
__global__ __launch_bounds__(256) void gather_kernel(
    const float* __restrict__ ea, const int* __restrict__ srcIdx,
    const int* __restrict__ row_start, const int* __restrict__ csr,
    const float* __restrict__ We, const float* __restrict__ Wskip,
    const float* __restrict__ bias, const float* __restrict__ h,
    const float* __restrict__ kb, const float* __restrict__ qb,
    const float* __restrict__ vb, float* __restrict__ hnew) {
    __shared__ float WeS[E_IN * D];   // 12.8 KB
    __shared__ float WsS[D * D];      // 16 KB
    int tid = threadIdx.y * 64 + threadIdx.x;
    for (int i = tid; i < E_IN * D; i += 256) WeS[i] = We[i];
    for (int i = tid; i < D * D; i += 256) WsS[i] = Wskip[i];
    __syncthreads();
    int d = threadIdx.x;
    int node = blockIdx.x * 4 + threadIdx.y;   // one wave (64 lanes) per node
    if (node >= N_NODES) return;
    int lo = row_start[node], hi = row_start[node + 1];
    float kv = kb[(long)node * D + d];
    float acc = 0.f;
    for (int idx = lo; idx < hi; ++idx) {
        int e = csr[idx];
        int s = srcIdx[e];
        float eav = (d < E_IN) ? ea[(long)e * E_IN + d] : 0.f;
        float ed0 = 0.f, ed1 = 0.f;
#pragma unroll
        for (int i = 0; i < E_IN; i += 2) {
            ed0 = fmaf(__shfl(eav, i),     WeS[i * D + d],       ed0);
            ed1 = fmaf(__shfl(eav, i + 1), WeS[(i + 1) * D + d], ed1);
        }
        float ed = ed0 + ed1;
        float qv = qb[(long)s * D + d];
        float vv = vb[(long)s * D + d];
        float gate = silu_f(kv + qv + 2.0f * ed);
        acc = fmaf(gate, vv + ed, acc);
    }
    // fused skip connection: h[node] @ Wskip
    float hv = h[(long)node * D + d];
    float a0 = 0.f, a1 = 0.f;
#pragma unroll
    for (int i = 0; i < D; i += 2) {
        a0 = fmaf(__shfl(hv, i),     WsS[i * D + d],       a0);
        a1 = fmaf(__shfl(hv, i + 1), WsS[(i + 1) * D + d], a1);
    }
    hnew[(long)node * D + d] = acc + a0 + a1 + bias[d];
}

// per-column sum & sumsq
__global__ __launch_bounds__(256) void bn_stats_kernel(
    const float* __restrict__ hnew, float* __restrict__ stats) {
    int d = threadIdx.x, yy = threadIdx.y;
    float s = 0.f, s2 = 0.f;
    for (int n = blockIdx.x * 4 + yy; n < N_NODES; n += gridDim.x * 4) {
        float v = hnew[(long)n * D + d];
        s += v;
        s2 = fmaf(v, v, s2);
    }
    __shared__ float ls[4][D], ls2[4][D];
    ls[yy][d] = s; ls2[yy][d] = s2;
    __syncthreads();
    if (yy == 0) {
        atomicAdd(&stats[d],     ls[0][d] + ls[1][d] + ls[2][d] + ls[3][d]);
        atomicAdd(&stats[D + d], ls2[0][d] + ls2[1][d] + ls2[2][d] + ls2[3][d]);
    }
}

__global__ __launch_bounds__(256) void bn_apply_kernel(
    const float* __restrict__ hnew, const float* __restrict__ stats,
    const float* __restrict__ gamma, const float* __restrict__ beta,
    float* __restrict__ h) {
    long idx = (long)blockIdx.x * 256 + threadIdx.x;
    if (idx >= (long)N_NODES * D) return;
    int d = (int)(idx & (D - 1));
    const float invN = 1.0f / (float)N_NODES;
    float mean = stats[d] * invN;
    float var = stats[D + d] * invN - mean * mean;
    float sc = rsqrtf(var + BN_EPS) * gamma[d];
    h[idx] = (hnew[idx] - mean) * sc + beta[d];
}

__global__ __launch_bounds__(256) void graph_bounds_kernel(
    const int* __restrict__ batch, int* __restrict__ start) {
    int n = blockIdx.x * 256 + threadIdx.x;
    if (n >= N_NODES) return;
    int b = batch[n];
    if (n == 0) {
        for (int g = 0; g <= b; ++g) start[g] = 0;
    } else {
        int p = batch[n - 1];
        for (int g = p + 1; g <= b; ++g) start[g] = n;
    }
    if (n == N_NODES - 1) {
        for (int g = b + 1; g <= N_GRAPHS; ++g) start[g] = N_NODES;
    }
}

__global__ __launch_bounds__(256) void pool_head_kernel(
    const float* __restrict__ h, const int* __restrict__ start,
    const float* __restrict__ pw, const float* __restrict__ pb,
    const float* __restrict__ ow, const float* __restrict__ ob,
    float* __restrict__ out) {
    int g = blockIdx.x;
    int d = threadIdx.x, yy = threadIdx.y;
    int lo = start[g], hi = start[g + 1];
    float s = 0.f;
    for (int n = lo + yy; n < hi; n += 4) s += h[(long)n * D + d];
    __shared__ float ls[4][D];
    ls[yy][d] = s;
    __syncthreads();
    __shared__ float grow[D];
    if (yy == 0) {
        float cnt = (float)(hi - lo);
        grow[d] = (ls[0][d] + ls[1][d] + ls[2][d] + ls[3][d]) / fmaxf(cnt, 1.0f);
    }
    __syncthreads();
    if (yy != 0) return;
    float acc = pb[d];
#pragma unroll 8
    for (int i = 0; i < D; ++i) acc = fmaf(grow[i], pw[i * D + d], acc);
    float sv = silu_f(acc) * ow[d];
    for (int off = 32; off > 0; off >>= 1) sv += __shfl_down(sv, off);
    if (d == 0) out[g] = sv + ob[0];
}

extern "C" void kernel_launch(void* const* d_in, const int* in_sizes, int n_in,
                              void* d_out, int out_size, void* d_ws, size_t ws_size,
                              hipStream_t stream) {
    const float* x        = (const float*)d_in[0];
    const int*   ei       = (const int*)d_in[1];
    const float* ea       = (const float*)d_in[2];
    const int*   batch    = (const int*)d_in[3];
    const float* pre_w    = (const float*)d_in[4];
    const float* pre_b    = (const float*)d_in[5];
    const float* Wk       = (const float*)d_in[6];
    const float* bk       = (const float*)d_in[7];
    const float* Wq       = (const float*)d_in[8];
    const float* bq       = (const float*)d_in[9];
    const float* Wv       = (const float*)d_in[10];
    const float* bv       = (const float*)d_in[11];
    const float* We       = (const float*)d_in[12];
    const float* Wskip    = (const float*)d_in[13];
    const float* conv_bias= (const float*)d_in[14];
    const float* bn_gamma = (const float*)d_in[15];
    const float* bn_beta  = (const float*)d_in[16];
    const float* post_w   = (const float*)d_in[17];
    const float* post_b   = (const float*)d_in[18];
    const float* out_w    = (const float*)d_in[19];
    const float* out_b    = (const float*)d_in[20];

    float* ws = (float*)d_ws;
    const size_t NH = (size_t)N_NODES * D;
    float* h     = ws;
    float* kb    = ws + NH;
    float* qb    = ws + 2 * NH;
    float* vb    = ws + 3 * NH;
    float* hnew  = ws + 4 * NH;
    float* stats = ws + 5 * NH;                      // 2*D floats
    int*   start = (int*)(ws + 5 * NH + 2 * D);      // N_GRAPHS+1
    int*   deg       = start + (N_GRAPHS + 1);       // N_NODES
    int*   row_start = deg + N_NODES;                // N_NODES+1
    int*   cursor    = row_start + (N_NODES + 1);    // N_NODES
    int*   csr       = cursor + N_NODES;             // N_EDGES

    const int* srcIdx = ei;
    const int* dstIdx = ei + N_EDGES;

    dim3 blk(64, 4);

    // CSR build (per launch; ws is re-poisoned each call)
    hipMemsetAsync(deg, 0, N_NODES * sizeof(int), stream);
    hist_kernel<<<1024, 256, 0, stream>>>(dstIdx, deg);
    scan_kernel<<<1, 1024, 0, stream>>>(deg, row_start, cursor);
    scatter_kernel<<<1024, 256, 0, stream>>>(dstIdx, cursor, csr);

    pre_fc_kernel<<<(N_NODES + 3) / 4, blk, 0, stream>>>(x, pre_w, pre_b, h);

    for (int l = 0; l < N_LAYERS; ++l) {
        node_proj_kernel<<<(N_NODES + 3) / 4, blk, 0, stream>>>(
            h, Wk + l * D * D, bk + l * D, Wq + l * D * D, bq + l * D,
            Wv + l * D * D, bv + l * D, kb, qb, vb);
        gather_kernel<<<(N_NODES + 3) / 4, blk, 0, stream>>>(
            ea, srcIdx, row_start, csr, We + l * E_IN * D, Wskip + l * D * D,
            conv_bias + l * D, h, kb, qb, vb, hnew);
        hipMemsetAsync(stats, 0, 2 * D * sizeof(float), stream);
        bn_stats_kernel<<<256, blk, 0, stream>>>(hnew, stats);
        bn_apply_kernel<<<(int)((NH + 255) / 256), 256, 0, stream>>>(
            hnew, stats, bn_gamma + l * D, bn_beta + l * D, h);
    }

    graph_bounds_kernel<<<(N_NODES + 255) / 256, 256, 0, stream>>>(batch, start);
    pool_head_kernel<<<N_GRAPHS, blk, 0, stream>>>(
        h, start, post_w, post_b, out_w, out_b, (float*)d_out);
}

// Round 3
// 3342.839 us; speedup vs baseline: 1.3586x; 1.3586x over previous
//
#include <hip/hip_runtime.h>
#include <math.h>

#define N_NODES 100000
#define N_EDGES 1600000
#define F_IN 92
#define E_IN 50
#define D 64
#define N_LAYERS 3
#define N_GRAPHS 512
#define BN_EPS 1e-5f

__device__ __forceinline__ float silu_f(float x) {
    return x / (1.0f + __expf(-x));
}

__device__ __forceinline__ float bcast_f(float v, int lane) {
    return __int_as_float(__builtin_amdgcn_readlane(__float_as_int(v), lane));
}

// ---------------- CSR build ----------------
__global__ __launch_bounds__(256) void hist_kernel(
    const int* __restrict__ dst, int* __restrict__ deg) {
    for (int e = blockIdx.x * 256 + threadIdx.x; e < N_EDGES; e += gridDim.x * 256)
        atomicAdd(&deg[dst[e]], 1);
}

__global__ __launch_bounds__(1024) void scan_kernel(
    const int* __restrict__ deg, int* __restrict__ row_start,
    int* __restrict__ cursor) {
    __shared__ int part[1024];
    int t = threadIdx.x;
    const int CH = (N_NODES + 1023) / 1024;
    int lo = t * CH, hi = min(lo + CH, N_NODES);
    int s = 0;
    for (int i = lo; i < hi; ++i) s += deg[i];
    part[t] = s;
    __syncthreads();
    for (int off = 1; off < 1024; off <<= 1) {
        int v = (t >= off) ? part[t - off] : 0;
        __syncthreads();
        part[t] += v;
        __syncthreads();
    }
    int base = (t == 0) ? 0 : part[t - 1];
    for (int i = lo; i < hi; ++i) {
        int dg = deg[i];
        row_start[i] = base;
        cursor[i] = base;
        base += dg;
    }
    if (t == 1023) row_start[N_NODES] = base;
}

__global__ __launch_bounds__(256) void scatter_kernel(
    const int* __restrict__ dst, int* __restrict__ cursor,
    int* __restrict__ csr) {
    for (int e = blockIdx.x * 256 + threadIdx.x; e < N_EDGES; e += gridDim.x * 256) {
        int pos = atomicAdd(&cursor[dst[e]], 1);
        csr[pos] = e;
    }
}

// permute ea and src into dst-sorted order (run once)
__global__ __launch_bounds__(256) void perm_kernel(
    const int* __restrict__ csr, const int* __restrict__ srcIdx,
    const float* __restrict__ ea, float* __restrict__ ea_s,
    int* __restrict__ src_s) {
    int d = threadIdx.x, yy = threadIdx.y;
    int p = blockIdx.x * 4 + yy;
    if (p >= N_EDGES) return;
    int e = csr[p];
    if (d == 0) src_s[p] = srcIdx[e];
    if (d < E_IN) ea_s[(long)p * E_IN + d] = ea[(long)e * E_IN + d];
}

// ---------------- dense stages ----------------
// h = silu(x @ pre_w + pre_b)
__global__ __launch_bounds__(256) void pre_fc_kernel(
    const float* __restrict__ x, const float* __restrict__ w,
    const float* __restrict__ b, float* __restrict__ h) {
    __shared__ float xs[4][F_IN];
    int d = threadIdx.x, yy = threadIdx.y;
    int node = blockIdx.x * 4 + yy;
    if (node < N_NODES) {
        const float* xrow = x + (long)node * F_IN;
        for (int i = d; i < F_IN; i += 64) xs[yy][i] = xrow[i];
    }
    __syncthreads();
    if (node >= N_NODES) return;
    float acc = b[d];
#pragma unroll 4
    for (int i = 0; i < F_IN; ++i) acc = fmaf(xs[yy][i], w[i * D + d], acc);
    h[(long)node * D + d] = silu_f(acc);
}

// Optional-BN-normalize input, then 4 fused GEMMs: k,q,v + skip(hnew=h@Ws+bias)
template <bool BN>
__global__ __launch_bounds__(256) void proj_kernel(
    const float* __restrict__ hin, const float* __restrict__ stats,
    const float* __restrict__ gamma, const float* __restrict__ beta,
    const float* __restrict__ Wk, const float* __restrict__ bk,
    const float* __restrict__ Wq, const float* __restrict__ bq,
    const float* __restrict__ Wv, const float* __restrict__ bv,
    const float* __restrict__ Ws, const float* __restrict__ cbias,
    float* __restrict__ ko, float* __restrict__ qo, float* __restrict__ vo,
    float* __restrict__ hnew) {
    __shared__ float hs[4][D];
    int d = threadIdx.x, yy = threadIdx.y;
    int node = blockIdx.x * 4 + yy;
    if (node < N_NODES) {
        float xv = hin[(long)node * D + d];
        if (BN) {
            const float invN = 1.0f / (float)N_NODES;
            float mean = stats[d] * invN;
            float var = stats[D + d] * invN - mean * mean;
            float sc = rsqrtf(var + BN_EPS) * gamma[d];
            xv = (xv - mean) * sc + beta[d];
        }
        hs[yy][d] = xv;
    }
    __syncthreads();
    if (node >= N_NODES) return;
    float ak = bk[d], aq = bq[d], av = bv[d], as = cbias[d];
#pragma unroll 8
    for (int i = 0; i < D; ++i) {
        float hv = hs[yy][i];
        ak = fmaf(hv, Wk[i * D + d], ak);
        aq = fmaf(hv, Wq[i * D + d], aq);
        av = fmaf(hv, Wv[i * D + d], av);
        as = fmaf(hv, Ws[i * D + d], as);
    }
    long off = (long)node * D + d;
    ko[off] = ak; qo[off] = aq; vo[off] = av; hnew[off] = as;
}

// One wave per node, pipelined edge loop. hnew[node] += sum_e silu(k+q+2e)*(v+e)
// PERM: ea/src pre-sorted by dst (indexed by CSR position p). !PERM: indexed by e=csr[p].
template <bool PERM>
__global__ __launch_bounds__(256) void gather_kernel(
    const float* __restrict__ ea, const int* __restrict__ srcArr,
    const int* __restrict__ csr, const int* __restrict__ row_start,
    const float* __restrict__ We,
    const float* __restrict__ kb, const float* __restrict__ qb,
    const float* __restrict__ vb, float* __restrict__ hnew) {
    int d = threadIdx.x;
    int node = blockIdx.x * 4 + threadIdx.y;
    if (node >= N_NODES) return;
    float WeReg[E_IN];  // We column d held in registers
#pragma unroll
    for (int i = 0; i < E_IN; ++i) WeReg[i] = We[i * D + d];
    int lo = row_start[node], hi = row_start[node + 1];
    float kv = kb[(long)node * D + d];
    float acc = 0.f;
    for (int base = lo; base < hi; base += 64) {
        int cnt = min(hi - base, 64);
        // lane j preloads indices for edge base+j (one vector gather)
        int e_l = 0, s_l = 0;
        if (d < cnt) {
            int p = base + d;
            e_l = PERM ? p : csr[p];
            s_l = PERM ? srcArr[p] : srcArr[e_l];
        }
        // 2-stage software pipeline over edges
        int s_c = __builtin_amdgcn_readlane(s_l, 0);
        int r_c = PERM ? base : __builtin_amdgcn_readlane(e_l, 0);
        float q_c = qb[(long)s_c * D + d];
        float v_c = vb[(long)s_c * D + d];
        float e_c = (d < E_IN) ? ea[(long)r_c * E_IN + d] : 0.f;
        for (int j = 0; j < cnt; ++j) {
            float q_n = 0.f, v_n = 0.f, e_n = 0.f;
            if (j + 1 < cnt) {
                int s_n = __builtin_amdgcn_readlane(s_l, j + 1);
                int r_n = PERM ? (base + j + 1) : __builtin_amdgcn_readlane(e_l, j + 1);
                q_n = qb[(long)s_n * D + d];
                v_n = vb[(long)s_n * D + d];
                e_n = (d < E_IN) ? ea[(long)r_n * E_IN + d] : 0.f;
            }
            float ed0 = 0.f, ed1 = 0.f;
#pragma unroll
            for (int i = 0; i < E_IN; i += 2) {
                ed0 = fmaf(bcast_f(e_c, i), WeReg[i], ed0);
                ed1 = fmaf(bcast_f(e_c, i + 1), WeReg[i + 1], ed1);
            }
            float ed = ed0 + ed1;
            float gate = silu_f(kv + q_c + 2.0f * ed);
            acc = fmaf(gate, v_c + ed, acc);
            q_c = q_n; v_c = v_n; e_c = e_n;
        }
    }
    long off = (long)node * D + d;
    hnew[off] += acc;
}

// per-column sum & sumsq
__global__ __launch_bounds__(256) void bn_stats_kernel(
    const float* __restrict__ hnew, float* __restrict__ stats) {
    int d = threadIdx.x, yy = threadIdx.y;
    float s = 0.f, s2 = 0.f;
    for (int n = blockIdx.x * 4 + yy; n < N_NODES; n += gridDim.x * 4) {
        float v = hnew[(long)n * D + d];
        s += v;
        s2 = fmaf(v, v, s2);
    }
    __shared__ float ls[4][D], ls2[4][D];
    ls[yy][d] = s; ls2[yy][d] = s2;
    __syncthreads();
    if (yy == 0) {
        atomicAdd(&stats[d],     ls[0][d] + ls[1][d] + ls[2][d] + ls[3][d]);
        atomicAdd(&stats[D + d], ls2[0][d] + ls2[1][d] + ls2[2][d] + ls2[3][d]);
    }
}

__global__ __launch_bounds__(256) void graph_bounds_kernel(
    const int* __restrict__ batch, int* __restrict__ start) {
    int n = blockIdx.x * 256 + threadIdx.x;
    if (n >= N_NODES) return;
    int b = batch[n];
    if (n == 0) {
        for (int g = 0; g <= b; ++g) start[g] = 0;
    } else {
        int p = batch[n - 1];
        for (int g = p + 1; g <= b; ++g) start[g] = n;
    }
    if (n == N_NODES - 1) {
        for (int g = b + 1; g <= N_GRAPHS; ++g) start[g] = N_NODES;
    }
}

// mean-pool(hnew) -> fused final-BN affine -> post FC + silu -> head
__global__ __launch_bounds__(256) void pool_head_kernel(
    const float* __restrict__ hnew, const int* __restrict__ start,
    const float* __restrict__ stats, const float* __restrict__ gamma,
    const float* __restrict__ beta,
    const float* __restrict__ pw, const float* __restrict__ pb,
    const float* __restrict__ ow, const float* __restrict__ ob,
    float* __restrict__ out) {
    int g = blockIdx.x;
    int d = threadIdx.x, yy = threadIdx.y;
    int lo = start[g], hi = start[g + 1];
    float s = 0.f;
    for (int n = lo + yy; n < hi; n += 4) s += hnew[(long)n * D + d];
    __shared__ float ls[4][D];
    ls[yy][d] = s;
    __syncthreads();
    __shared__ float grow[D];
    if (yy == 0) {
        float tot = ls[0][d] + ls[1][d] + ls[2][d] + ls[3][d];
        float gd = 0.f;
        if (hi > lo) {  // BN is affine; affine(mean) == mean(affine). empty graph -> 0
            float m = tot / (float)(hi - lo);
            const float invN = 1.0f / (float)N_NODES;
            float mean = stats[d] * invN;
            float var = stats[D + d] * invN - mean * mean;
            float sc = rsqrtf(var + BN_EPS) * gamma[d];
            gd = (m - mean) * sc + beta[d];
        }
        grow[d] = gd;
    }
    __syncthreads();
    if (yy != 0) return;
    float accp = pb[d];
#pragma unroll 8
    for (int i = 0; i < D; ++i) accp = fmaf(grow[i], pw[i * D + d], accp);
    float sv = silu_f(accp) * ow[d];
    for (int off = 32; off > 0; off >>= 1) sv += __shfl_down(sv, off);
    if (d == 0) out[g] = sv + ob[0];
}

extern "C" void kernel_launch(void* const* d_in, const int* in_sizes, int n_in,
                              void* d_out, int out_size, void* d_ws, size_t ws_size,
                              hipStream_t stream) {
    const float* x        = (const float*)d_in[0];
    const int*   ei       = (const int*)d_in[1];
    const float* ea       = (const float*)d_in[2];
    const int*   batch    = (const int*)d_in[3];
    const float* pre_w    = (const float*)d_in[4];
    const float* pre_b    = (const float*)d_in[5];
    const float* Wk       = (const float*)d_in[6];
    const float* bk       = (const float*)d_in[7];
    const float* Wq       = (const float*)d_in[8];
    const float* bq       = (const float*)d_in[9];
    const float* Wv       = (const float*)d_in[10];
    const float* bv       = (const float*)d_in[11];
    const float* We       = (const float*)d_in[12];
    const float* Wskip    = (const float*)d_in[13];
    const float* conv_bias= (const float*)d_in[14];
    const float* bn_gamma = (const float*)d_in[15];
    const float* bn_beta  = (const float*)d_in[16];
    const float* post_w   = (const float*)d_in[17];
    const float* post_b   = (const float*)d_in[18];
    const float* out_w    = (const float*)d_in[19];
    const float* out_b    = (const float*)d_in[20];

    float* ws = (float*)d_ws;
    const size_t NH = (size_t)N_NODES * D;
    float* bufA  = ws;
    float* bufB  = ws + NH;
    float* kb    = ws + 2 * NH;
    float* qb    = ws + 3 * NH;
    float* vb    = ws + 4 * NH;
    float* stats = ws + 5 * NH;                          // 3 * 2*D floats
    int*   start     = (int*)(stats + 6 * D);            // N_GRAPHS+1
    int*   deg       = start + (N_GRAPHS + 1);           // N_NODES
    int*   row_start = deg + N_NODES;                    // N_NODES+1
    int*   cursor    = row_start + (N_NODES + 1);        // N_NODES
    int*   csr       = cursor + N_NODES;                 // N_EDGES
    // optional permuted-edge region (aligned)
    size_t off_b = (size_t)((char*)(csr + N_EDGES) - (char*)d_ws);
    off_b = (off_b + 63) & ~(size_t)63;
    float* ea_s  = (float*)((char*)d_ws + off_b);        // N_EDGES * E_IN
    int*   src_s = (int*)(ea_s + (size_t)N_EDGES * E_IN);// N_EDGES
    size_t need  = (size_t)((char*)(src_s + N_EDGES) - (char*)d_ws);
    const bool use_perm = ws_size >= need;

    const int* srcIdx = ei;
    const int* dstIdx = ei + N_EDGES;

    dim3 blk(64, 4);
    const int NB_N = (N_NODES + 3) / 4;

    // CSR build
    hipMemsetAsync(deg, 0, N_NODES * sizeof(int), stream);
    hipMemsetAsync(stats, 0, 6 * D * sizeof(float), stream);
    hist_kernel<<<1024, 256, 0, stream>>>(dstIdx, deg);
    scan_kernel<<<1, 1024, 0, stream>>>(deg, row_start, cursor);
    scatter_kernel<<<1024, 256, 0, stream>>>(dstIdx, cursor, csr);
    if (use_perm)
        perm_kernel<<<(N_EDGES + 3) / 4, blk, 0, stream>>>(csr, srcIdx, ea, ea_s, src_s);

    pre_fc_kernel<<<NB_N, blk, 0, stream>>>(x, pre_w, pre_b, bufA);

    float* hin = bufA;
    float* hout = bufB;
    for (int l = 0; l < N_LAYERS; ++l) {
        if (l == 0)
            proj_kernel<false><<<NB_N, blk, 0, stream>>>(
                hin, nullptr, nullptr, nullptr,
                Wk + l * D * D, bk + l * D, Wq + l * D * D, bq + l * D,
                Wv + l * D * D, bv + l * D, Wskip + l * D * D, conv_bias + l * D,
                kb, qb, vb, hout);
        else
            proj_kernel<true><<<NB_N, blk, 0, stream>>>(
                hin, stats + (l - 1) * 2 * D, bn_gamma + (l - 1) * D, bn_beta + (l - 1) * D,
                Wk + l * D * D, bk + l * D, Wq + l * D * D, bq + l * D,
                Wv + l * D * D, bv + l * D, Wskip + l * D * D, conv_bias + l * D,
                kb, qb, vb, hout);
        if (use_perm)
            gather_kernel<true><<<NB_N, blk, 0, stream>>>(
                ea_s, src_s, csr, row_start, We + l * E_IN * D, kb, qb, vb, hout);
        else
            gather_kernel<false><<<NB_N, blk, 0, stream>>>(
                ea, srcIdx, csr, row_start, We + l * E_IN * D, kb, qb, vb, hout);
        bn_stats_kernel<<<256, blk, 0, stream>>>(hout, stats + l * 2 * D);
        float* t = hin; hin = hout; hout = t;
    }

    graph_bounds_kernel<<<(N_NODES + 255) / 256, 256, 0, stream>>>(batch, start);
    // hin now points to the last layer's hnew
    pool_head_kernel<<<N_GRAPHS, blk, 0, stream>>>(
        hin, start, stats + (N_LAYERS - 1) * 2 * D,
        bn_gamma + (N_LAYERS - 1) * D, bn_beta + (N_LAYERS - 1) * D,
        post_w, post_b, out_w, out_b, (float*)d_out);
}